// Round 3
// baseline (472.934 us; speedup 1.0000x reference)
//
#include <hip/hip_runtime.h>
#include <stdint.h>

typedef unsigned short u16;
typedef unsigned int   u32;
typedef int v4i __attribute__((ext_vector_type(4)));

static constexpr int Bd = 4096;   // batch
static constexpr int Kd = 2048;   // in-features (GEMM K)
static constexpr int Fd = 4096;   // out-features

// Workspace (bytes). yr aliases X1B+W1B (dead before GEMM writes).
static constexpr size_t OFF_QX   = 0;          // i8 [4096*2048]              (8 MB)
static constexpr size_t OFF_QWT  = 8388608;    // i8 [4096*2048] transposed   (8 MB)
static constexpr size_t OFF_X1B  = 16777216;   // u32[4096*1024] bf16 pairs   (16 MB)
static constexpr size_t OFF_W1B  = 33554432;   // u32[2048*2048] bf16 pairs   (16 MB)
static constexpr size_t OFF_YR   = 16777216;   // u16[4096*4096] aliases X1B/W1B (32 MB)
static constexpr size_t OFF_SCAL = 83886080;   // 2x u32 (max|X1|, max|W1| float bits)

// ---------------- FWHT helpers ----------------
__device__ __forceinline__ void fwht16(float* v) {
#pragma unroll
  for (int b = 1; b < 16; b <<= 1) {
#pragma unroll
    for (int i = 0; i < 16; ++i) {
      if (!(i & b)) { float a = v[i]; float c = v[i | b]; v[i] = a + c; v[i | b] = a - c; }
    }
  }
}
__device__ __forceinline__ void fwht64(float* v) {
#pragma unroll
  for (int b = 1; b < 64; b <<= 1) {
#pragma unroll
    for (int i = 0; i < 64; ++i) {
      if (!(i & b)) { float a = v[i]; float c = v[i | b]; v[i] = a + c; v[i | b] = a - c; }
    }
  }
}

// ---------------- bf16 pack/unpack ----------------
__device__ __forceinline__ void unpack2(u32 u, float& a, float& b) {
  a = __uint_as_float(u << 16);
  b = __uint_as_float(u & 0xffff0000u);
}
__device__ __forceinline__ u16 bf16_rne(float f) {
  u32 x = __float_as_uint(f);
  return (u16)(((x + 0x7fffu + ((x >> 16) & 1u)) >> 16) & 0xffffu);
}
__device__ __forceinline__ u32 pack2(float a, float b) {
  u32 x = __float_as_uint(a), y = __float_as_uint(b);
  u32 lo = ((x + 0x7fffu + ((x >> 16) & 1u)) >> 16) & 0xffffu;
  u32 hi = (y + 0x7fffu + ((y >> 16) & 1u)) & 0xffff0000u;
  return lo | hi;
}

// ---------------- x-path stage 1: H64 on consecutive 64-row groups, f32->bf16 -------
__global__ __launch_bounds__(256) void xcol_s1(const float2* __restrict__ x,
                                               u32* __restrict__ X1b,
                                               u32* __restrict__ scal) {
  if (blockIdx.x == 0 && blockIdx.y == 0 && threadIdx.x < 2) scal[threadIdx.x] = 0u;
  const int t = threadIdx.x;
  const int cp = blockIdx.x * 256 + t;       // col pair 0..1023
  const int base = blockIdx.y * 64;
  float va[64], vb[64];
#pragma unroll
  for (int r = 0; r < 64; ++r) {
    float2 xv = x[(size_t)(base + r) * 1024 + cp];
    va[r] = xv.x; vb[r] = xv.y;
  }
  fwht64(va); fwht64(vb);
#pragma unroll
  for (int r = 0; r < 64; ++r)
    X1b[(size_t)(base + r) * 1024 + cp] = pack2(va[r], vb[r]);
}

// ---------------- x-path stage 2: H64 on stride-64 rows, in-place bf16, + max -------
__global__ __launch_bounds__(256) void xcol_s2(u32* __restrict__ X1b,
                                               u32* __restrict__ gmax) {
  __shared__ float red[4];
  const int t = threadIdx.x;
  const int cp = blockIdx.x * 256 + t;
  const int base = blockIdx.y;               // 0..63
  float va[64], vb[64];
#pragma unroll
  for (int r = 0; r < 64; ++r)
    unpack2(X1b[(size_t)(base + r * 64) * 1024 + cp], va[r], vb[r]);
  fwht64(va); fwht64(vb);
  float m = 0.f;
#pragma unroll
  for (int r = 0; r < 64; ++r) {
    X1b[(size_t)(base + r * 64) * 1024 + cp] = pack2(va[r], vb[r]);
    m = fmaxf(m, fmaxf(fabsf(va[r]), fabsf(vb[r])));
  }
#pragma unroll
  for (int off = 32; off > 0; off >>= 1) m = fmaxf(m, __shfl_down(m, off));
  if ((t & 63) == 0) red[t >> 6] = m;
  __syncthreads();
  if (t == 0) {
    m = fmaxf(fmaxf(red[0], red[1]), fmaxf(red[2], red[3]));
    atomicMax(gmax, __float_as_uint(m));
  }
}

// ---------------- w-path: full FWHT-4096 per row, f32 in -> bf16 out, + max --------
__global__ __launch_bounds__(256) void roww_fwht(const float* __restrict__ in,
                                                 u32* __restrict__ W1b,
                                                 u32* __restrict__ gmax) {
  __shared__ float s[4224];
  __shared__ float red[4];
  const int t = threadIdx.x;
  const size_t rowoff = (size_t)blockIdx.x * 4096;
  float v[16];
#pragma unroll
  for (int j = 0; j < 16; ++j) v[j] = in[rowoff + ((j << 8) | t)];
  fwht16(v);
#pragma unroll
  for (int j = 0; j < 16; ++j) { int e = (j << 8) | t; s[e + (e >> 5)] = v[j]; }
  __syncthreads();
#pragma unroll
  for (int j = 0; j < 16; ++j) { int e = ((t >> 4) << 8) | (j << 4) | (t & 15); v[j] = s[e + (e >> 5)]; }
  fwht16(v);
#pragma unroll
  for (int j = 0; j < 16; ++j) { int e = ((t >> 4) << 8) | (j << 4) | (t & 15); s[e + (e >> 5)] = v[j]; }
  __syncthreads();
#pragma unroll
  for (int j = 0; j < 16; ++j) { int e = (t << 4) | j; v[j] = s[e + (e >> 5)]; }
  fwht16(v);
  // store as bf16 pairs: cols t*16 .. t*16+15
  uint4 o0, o1;
  o0.x = pack2(v[0], v[1]);   o0.y = pack2(v[2], v[3]);
  o0.z = pack2(v[4], v[5]);   o0.w = pack2(v[6], v[7]);
  o1.x = pack2(v[8], v[9]);   o1.y = pack2(v[10], v[11]);
  o1.z = pack2(v[12], v[13]); o1.w = pack2(v[14], v[15]);
  uint4* op = (uint4*)(W1b + (size_t)blockIdx.x * 2048 + t * 8);
  op[0] = o0; op[1] = o1;
  float m = 0.f;
#pragma unroll
  for (int j = 0; j < 16; ++j) m = fmaxf(m, fabsf(v[j]));
#pragma unroll
  for (int off = 32; off > 0; off >>= 1) m = fmaxf(m, __shfl_down(m, off));
  if ((t & 63) == 0) red[t >> 6] = m;
  __syncthreads();
  if (t == 0) {
    m = fmaxf(fmaxf(red[0], red[1]), fmaxf(red[2], red[3]));
    atomicMax(gmax, __float_as_uint(m));
  }
}

// ---------------- Stochastic quantization ----------------
__device__ __forceinline__ float quant1(float X1, float nz, float s) {
  float xr = X1 * 0.015625f;         // /64, exact
  float xs = xr / s;
  float f  = floorf(xs);
  float q  = f + ((nz < (xs - f)) ? 1.0f : 0.0f);
  return fminf(fmaxf(q, -127.0f), 127.0f);
}
__device__ __forceinline__ u32 pk4(float a, float b, float c, float d) {
  return ((u32)(unsigned char)(char)(int)a)        |
         (((u32)(unsigned char)(char)(int)b) << 8) |
         (((u32)(unsigned char)(char)(int)c) << 16)|
         (((u32)(unsigned char)(char)(int)d) << 24);
}

__global__ __launch_bounds__(256) void quant_x_i8(const uint4* __restrict__ X1b,
                                                  const float4* __restrict__ nz,
                                                  uint2* __restrict__ qx,
                                                  const u32* __restrict__ scal) {
  size_t g = (size_t)blockIdx.x * 256 + threadIdx.x;
  float s = (__uint_as_float(scal[0]) * 0.015625f) / 127.0f;
  uint4 xv = X1b[g];
  float4 na = nz[2 * g], nb = nz[2 * g + 1];
  float a, b, c, d, e, f, gg, h;
  unpack2(xv.x, a, b);  unpack2(xv.y, c, d);
  unpack2(xv.z, e, f);  unpack2(xv.w, gg, h);
  u32 lo = pk4(quant1(a, na.x, s), quant1(b, na.y, s), quant1(c, na.z, s), quant1(d, na.w, s));
  u32 hi = pk4(quant1(e, nb.x, s), quant1(f, nb.y, s), quant1(gg, nb.z, s), quant1(h, nb.w, s));
  qx[g] = make_uint2(lo, hi);
}

// Quantize W1b [K,F] (bf16 pairs) and write transposed i8 [F,K].
__global__ __launch_bounds__(256) void quant_w_t_i8(const u32* __restrict__ W1b,
                                                    const float2* __restrict__ nz,
                                                    char* __restrict__ qwT,
                                                    const u32* __restrict__ scal) {
  __shared__ float tile[64][65];
  const int t = threadIdx.x;
  const int k0 = blockIdx.x * 64;   // over K=2048
  const int n0 = blockIdx.y * 64;   // over F=4096
  float s = (__uint_as_float(scal[1]) * 0.015625f) / 127.0f;
#pragma unroll
  for (int i = 0; i < 8; ++i) {
    int idx = t + 256 * i;          // 0..2047 over (k, np)
    int k = idx >> 5, np = idx & 31;
    u32 u = W1b[(size_t)(k0 + k) * 2048 + (n0 >> 1) + np];
    float2 nv = nz[(size_t)(k0 + k) * 2048 + (n0 >> 1) + np];
    float a, b; unpack2(u, a, b);
    tile[k][2 * np]     = quant1(a, nv.x, s);
    tile[k][2 * np + 1] = quant1(b, nv.y, s);
  }
  __syncthreads();
  const int kq = t & 15, nb = t >> 4;
#pragma unroll
  for (int i = 0; i < 4; ++i) {
    int n = nb + 16 * i;
    u32 p = pk4(tile[4 * kq + 0][n], tile[4 * kq + 1][n],
                tile[4 * kq + 2][n], tile[4 * kq + 3][n]);
    *(u32*)(qwT + (size_t)(n0 + n) * Kd + k0 + 4 * kq) = p;
  }
}

// ---------------- GEMM (i8 MFMA, 256x256 tile, 8-wave, 1-phase-lookahead pipeline) --
__device__ __forceinline__ void async16(const void* g, void* l) {
  __builtin_amdgcn_global_load_lds((__attribute__((address_space(1))) void*)(g),
                                   (__attribute__((address_space(3))) void*)(l),
                                   16, 0, 0);
}

// Stage A half h (rows [h*128, h*128+128)), K-tile kt. Linear LDS dest; source
// column pre-swizzled so the XOR-swizzled ds_read is conflict-free.
__device__ __forceinline__ void stage_a(const char* __restrict__ A, char* dst,
                                        int m0, int h, int kt, int w, int lr, int sx) {
#pragma unroll
  for (int j = 0; j < 2; ++j) {
    const int rl = h * 128 + j * 64 + w * 8;   // wave-uniform LDS row base
    async16(A + (size_t)(m0 + rl + lr) * 2048 + kt * 128 + sx * 16, dst + rl * 128);
  }
}
// Stage B half h = rows with bit5 == h (4 chunks of 32 at stride 64), K-tile kt.
__device__ __forceinline__ void stage_b(const char* __restrict__ Bt, char* dst,
                                        int n0, int h, int kt, int w, int lr, int sx) {
#pragma unroll
  for (int j = 0; j < 2; ++j) {
    const int n = j * 8 + w;                   // instruction id 0..15
    const int rl = (n >> 2) * 64 + h * 32 + (n & 3) * 8;
    async16(Bt + (size_t)(n0 + rl + lr) * 2048 + kt * 128 + sx * 16, dst + rl * 128);
  }
}

#define VMW(N) asm volatile("s_waitcnt vmcnt(" #N ")" ::: "memory")

// ds_read A fragments (QM half) into SET[4][2]
#define RAV(SET, BASE, QM) do {                                                \
  _Pragma("unroll") for (int mi_ = 0; mi_ < 4; ++mi_) {                        \
    SET[mi_][0] = *(const v4i*)((BASE) + (QM) * 16384 + aoff + mi_ * 2048 + c0);\
    SET[mi_][1] = *(const v4i*)((BASE) + (QM) * 16384 + aoff + mi_ * 2048 + c1);\
  } } while (0)
// ds_read B fragments (QN half) into SET[2][2]
#define RBV(SET, BASE, QN) do {                                                \
  _Pragma("unroll") for (int ni_ = 0; ni_ < 2; ++ni_) {                        \
    SET[ni_][0] = *(const v4i*)((BASE) + (QN) * 4096 + boff + ni_ * 2048 + c0);\
    SET[ni_][1] = *(const v4i*)((BASE) + (QN) * 4096 + boff + ni_ * 2048 + c1);\
  } } while (0)

// barrier -> MFMA quadrant -> barrier (frags loaded one phase earlier; the
// compiler inserts the precise lgkmcnt before first frag use)
#define MFQ(QM, QN, AS, BS) do {                                               \
  __builtin_amdgcn_sched_barrier(0);                                           \
  __builtin_amdgcn_s_barrier();                                                \
  __builtin_amdgcn_s_setprio(1);                                               \
  _Pragma("unroll") for (int kc_ = 0; kc_ < 2; ++kc_)                          \
  _Pragma("unroll") for (int mi_ = 0; mi_ < 4; ++mi_)                          \
  _Pragma("unroll") for (int ni_ = 0; ni_ < 2; ++ni_)                          \
    acc[QM][QN][mi_][ni_] = __builtin_amdgcn_mfma_i32_16x16x64_i8(             \
        AS[mi_][kc_], BS[ni_][kc_], acc[QM][QN][mi_][ni_], 0, 0, 0);           \
  __builtin_amdgcn_s_setprio(0);                                               \
  __builtin_amdgcn_s_barrier();                                                \
  __builtin_amdgcn_sched_barrier(0);                                           \
  } while (0)

__global__ __launch_bounds__(512, 1) void gemm_i8(const char* __restrict__ A,   // [4096,2048] i8
                                                  const char* __restrict__ Bt,  // [4096,2048] i8
                                                  u16* __restrict__ C,          // [4096,4096] bf16
                                                  const u32* __restrict__ scal) {
  // NOTE: launch_bounds(512,1): LDS (128 KB) already caps residency at 1 block/CU,
  // so a tighter waves/EU claim only caps VGPRs and forces acc spills to scratch
  // (R1/R2 showed +6..20 MB of WRITE_SIZE above the 32 MB C output).
  __shared__ __align__(16) char As0[32768];  // even-tile A: [256 rows][128 B]
  __shared__ __align__(16) char As1[32768];  // odd-tile A
  __shared__ __align__(16) char Bs0[32768];  // even-tile B
  __shared__ __align__(16) char Bs1[32768];  // odd-tile B
  const int t = threadIdx.x;
  const int w = t >> 6, l = t & 63;
  const int l15 = l & 15, quad = l >> 4;
  const int ls = l & 7, lr = l >> 3;
  const int sxr = ls ^ lr;                  // staging source-column swizzle
  const int wm = w & 1, wn = w >> 1;        // 2 (M) x 4 (N) wave grid

  // read-side precomputed offsets
  const int aoff = (wm * 64 + l15) * 128;
  const int boff = (wn * 64 + l15) * 128;
  const int c0 = (quad ^ ls) * 16;
  const int c1 = ((4 + quad) ^ ls) * 16;

  // gm=8 panel swizzle over the 16x16 tile grid (grid = 256 blocks, 1/CU)
  int pid = blockIdx.x;
  const int GM = 8;
  int gid = pid / (GM * 16);
  int mm = gid * GM + (pid % GM);
  int nn = (pid % (GM * 16)) / GM;
  const int m0 = mm * 256, n0 = nn * 256;

  v4i acc[2][2][4][2] = {};   // [qm][qn][mi][ni]
  v4i aA[4][2], aB[4][2];     // A frag double-sets [mi][kc]
  v4i bA[2][2], bB[2][2];     // B frag double-sets [ni][kc]

  // ---- prologue: tile0 fully staged; read (av0,bv0); tile1 {A0,B0} in flight ----
  stage_a(A,  As0, m0, 0, 0, w, lr, sxr);
  stage_b(Bt, Bs0, n0, 0, 0, w, lr, sxr);
  stage_a(A,  As0, m0, 1, 0, w, lr, sxr);
  stage_b(Bt, Bs0, n0, 1, 0, w, lr, sxr);
  VMW(0);
  __builtin_amdgcn_s_barrier();
  RAV(aA, As0, 0);                      // av0(0)
  RBV(bA, Bs0, 0);                      // bv0(0)
  stage_a(A,  As1, m0, 0, 1, w, lr, sxr);
  stage_b(Bt, Bs1, n0, 0, 1, w, lr, sxr);

#pragma unroll 1
  for (int i = 0; i < 8; ++i) {
    const int a = 2 * i, b = 2 * i + 1;
    const int a2 = a + 2, b2 = b + 2;
    const bool more = (i < 7);
    // ---- tile a (even, buf0) ----
    // Ph0: consume (aA,bA)=(av0(a),bv0(a)); prefetch bv1(a)
    stage_a(A, As1, m0, 1, b, w, lr, sxr);                 // A1(b)
    VMW(8);
    RBV(bB, Bs0, 1);
    MFQ(0, 0, aA, bA);
    // Ph1: consume (aA,bB); prefetch av1(a)
    stage_b(Bt, Bs1, n0, 1, b, w, lr, sxr);                // B1(b)
    VMW(6);
    RAV(aB, As0, 1);
    MFQ(0, 1, aA, bB);
    // Ph2: consume (aB,bB); prefetch av0(b)
    if (more) { stage_a(A, As0, m0, 0, a2, w, lr, sxr); VMW(6); }  // A0(a+2)
    else      { VMW(4); }
    RAV(aA, As1, 0);
    MFQ(1, 1, aB, bB);
    // Ph3: consume (aB,bA); prefetch bv0(b)
    if (more) { stage_b(Bt, Bs0, n0, 0, a2, w, lr, sxr); VMW(4); } // B0(a+2)
    else      { VMW(0); }
    RBV(bB, Bs1, 0);
    MFQ(1, 0, aB, bA);
    // ---- tile b (odd, buf1) ----
    // Ph4: consume (aA,bB)=(av0(b),bv0(b)); prefetch bv1(b)
    if (more) { stage_a(A, As0, m0, 1, a2, w, lr, sxr); VMW(8); }  // A1(a+2)
    RBV(bA, Bs1, 1);
    MFQ(0, 0, aA, bB);
    // Ph5: consume (aA,bA); prefetch av1(b)
    if (more) { stage_b(Bt, Bs0, n0, 1, a2, w, lr, sxr); VMW(6); } // B1(a+2)
    RAV(aB, As1, 1);
    MFQ(0, 1, aA, bA);
    // Ph6: consume (aB,bA); prefetch av0(a+2)
    if (more) {
      stage_a(A, As1, m0, 0, b2, w, lr, sxr);                      // A0(b+2)
      VMW(6);
      RAV(aA, As0, 0);
    }
    MFQ(1, 1, aB, bA);
    // Ph7: consume (aB,bB); prefetch bv0(a+2)
    if (more) {
      stage_b(Bt, Bs1, n0, 0, b2, w, lr, sxr);                     // B0(b+2)
      VMW(4);
      RBV(bA, Bs0, 0);
    }
    MFQ(1, 0, aB, bB);
  }

  float sx = (__uint_as_float(scal[0]) * 0.015625f) / 127.0f;
  float sw = (__uint_as_float(scal[1]) * 0.015625f) / 127.0f;
  float alpha = sx * sw * (1.0f / 4096.0f);

  // ---- fused epilogue: H64 over row-low and col-low bits, per 64x64 block ----
  // Per wave: 128x64 output = two (qm) 64x64 blocks. Register bits {r,ni,qn,mi}
  // -> flat fwht64 (order-free); lane bits {l15: col 0-3, quad: row 2-3} -> 6
  // shfl_xor butterflies. row%64 = mi*16+quad*4+r, col%64 = qn*32+ni*16+l15.
#pragma unroll
  for (int qm = 0; qm < 2; ++qm) {
    float vals[64];
#pragma unroll
    for (int mi = 0; mi < 4; ++mi)
#pragma unroll
      for (int qn = 0; qn < 2; ++qn)
#pragma unroll
        for (int ni = 0; ni < 2; ++ni)
#pragma unroll
          for (int r = 0; r < 4; ++r)
            vals[mi * 16 + qn * 8 + ni * 4 + r] = (float)acc[qm][qn][mi][ni][r] * alpha;
    fwht64(vals);
#pragma unroll
    for (int k = 0; k < 6; ++k) {
      const int mask = 1 << k;
      const int bit = (l >> k) & 1;
#pragma unroll
      for (int ii = 0; ii < 64; ++ii) {
        float p = __shfl_xor(vals[ii], mask, 64);
        vals[ii] = bit ? (p - vals[ii]) : (vals[ii] + p);
      }
    }
#pragma unroll
    for (int mi = 0; mi < 4; ++mi)
#pragma unroll
      for (int qn = 0; qn < 2; ++qn)
#pragma unroll
        for (int ni = 0; ni < 2; ++ni)
#pragma unroll
          for (int r = 0; r < 4; ++r) {
            int row = m0 + qm * 128 + wm * 64 + mi * 16 + quad * 4 + r;
            int col = n0 + wn * 64 + qn * 32 + ni * 16 + l15;
            C[(size_t)row * Fd + col] = bf16_rne(vals[mi * 16 + qn * 8 + ni * 4 + r]);
          }
  }
}

// ---------------- Output pass Ch: H64 over col-high bits, per-row, bf16 in-place ----
__global__ __launch_bounds__(256) void colhigh_fwht(u16* __restrict__ yr) {
  __shared__ u16 sh[4 * 4096];   // 32768 B = 2048 uint4 -> 8 iters of 256 threads
  const int t = threadIdx.x;
  const size_t row0 = (size_t)blockIdx.x * 4;
  uint4* shv = (uint4*)sh;
  const uint4* g = (const uint4*)(yr + row0 * 4096);
#pragma unroll
  for (int i = 0; i < 8; ++i) shv[t + 256 * i] = g[t + 256 * i];
  __syncthreads();
  const int grp = t >> 6, cl = t & 63;
  const u16* shr = sh + grp * 4096;
  float v[64];
#pragma unroll
  for (int ch = 0; ch < 64; ++ch)
    v[ch] = __uint_as_float(((u32)shr[ch * 64 + cl]) << 16);
  fwht64(v);
  __syncthreads();
  u16* shw = sh + grp * 4096;
#pragma unroll
  for (int ch = 0; ch < 64; ++ch)
    shw[ch * 64 + cl] = bf16_rne(v[ch]);
  __syncthreads();
  uint4* go = (uint4*)(yr + row0 * 4096);
#pragma unroll
  for (int i = 0; i < 8; ++i) go[t + 256 * i] = shv[t + 256 * i];
}

// ---------------- Output pass Rh (LAST): H64 over stride-64 rows, +bias, f32 out ----
__global__ __launch_bounds__(256, 1) void rowhigh_last(const u32* __restrict__ in,
                                                       float* __restrict__ outf,
                                                       const float* __restrict__ bias) {
  const int t = threadIdx.x;
  const int cp = blockIdx.x * 256 + t;      // column-pair 0..2047
  const int base = blockIdx.y;              // 0..63
  float va[64], vb[64];
#pragma unroll
  for (int r = 0; r < 64; ++r)
    unpack2(in[(size_t)(base + r * 64) * 2048 + cp], va[r], vb[r]);
  fwht64(va);
  fwht64(vb);
  float b0 = bias[2 * cp], b1 = bias[2 * cp + 1];
#pragma unroll
  for (int r = 0; r < 64; ++r) {
    int row = base + r * 64;
    float2 o = make_float2(va[r] + b0, vb[r] + b1);
    *(float2*)&outf[(size_t)row * 4096 + 2 * cp] = o;
  }
}

// ---------------- Launch ----------------
extern "C" void kernel_launch(void* const* d_in, const int* in_sizes, int n_in,
                              void* d_out, int out_size, void* d_ws, size_t ws_size,
                              hipStream_t stream) {
  (void)in_sizes; (void)n_in; (void)out_size; (void)ws_size;
  const float* x       = (const float*)d_in[0];  // [4096,2048]
  const float* w       = (const float*)d_in[1];  // [2048,4096]
  const float* bias    = (const float*)d_in[2];  // [4096]
  const float* noise_x = (const float*)d_in[5];  // [4096,2048]
  const float* noise_w = (const float*)d_in[6];  // [2048,4096]
  char* ws = (char*)d_ws;
  char* qx   = (char*)(ws + OFF_QX);
  char* qwT  = (char*)(ws + OFF_QWT);
  u32*  X1b  = (u32*) (ws + OFF_X1B);
  u32*  W1b  = (u32*) (ws + OFF_W1B);
  u16*  yr   = (u16*) (ws + OFF_YR);
  u32*  scal = (u32*) (ws + OFF_SCAL);
  float* out = (float*)d_out;

  // x rotation: H2 @ x (2 stages, bf16 intermediate); stage1 also zeroes scal
  xcol_s1<<<dim3(4, 64), dim3(256), 0, stream>>>((const float2*)x, X1b, scal);
  xcol_s2<<<dim3(4, 64), dim3(256), 0, stream>>>(X1b, scal + 0);
  // w rotation: w @ H1 (row FWHT, bf16 out) + max
  roww_fwht<<<dim3(Kd), dim3(256), 0, stream>>>(w, W1b, scal + 1);
  // stochastic int8 quantization
  quant_x_i8<<<dim3(4096), dim3(256), 0, stream>>>(
      (const uint4*)X1b, (const float4*)noise_x, (uint2*)qx, scal);
  quant_w_t_i8<<<dim3(Kd / 64, Fd / 64), dim3(256), 0, stream>>>(
      W1b, (const float2*)noise_w, qwT, scal);
  // core i8 GEMM (256^2 tile, lookahead pipeline) -> yr bf16 + fused Rl/Cl rotation
  gemm_i8<<<dim3((Bd / 256) * (Fd / 256)), dim3(512), 0, stream>>>(qx, qwT, yr, scal);
  // remaining output stages: col-high, then row-high (+bias, f32)
  colhigh_fwht<<<dim3(Bd / 4), dim3(256), 0, stream>>>(yr);
  rowhigh_last<<<dim3(8, 64), dim3(256), 0, stream>>>((const u32*)yr, out, bias);
}

// Round 4
// 362.146 us; speedup vs baseline: 1.3059x; 1.3059x over previous
//
#include <hip/hip_runtime.h>
#include <stdint.h>

typedef unsigned short u16;
typedef unsigned int   u32;
typedef int v4i __attribute__((ext_vector_type(4)));

static constexpr int Bd = 4096;   // batch
static constexpr int Kd = 2048;   // in-features (GEMM K)
static constexpr int Fd = 4096;   // out-features

// Workspace (bytes). yr aliases X1B+W1B (dead before GEMM writes).
static constexpr size_t OFF_QX   = 0;          // i8 [4096*2048]              (8 MB)
static constexpr size_t OFF_QWT  = 8388608;    // i8 [4096*2048] transposed   (8 MB)
static constexpr size_t OFF_X1B  = 16777216;   // u16[4096*2048] bf16         (16 MB)
static constexpr size_t OFF_W1B  = 33554432;   // u32[2048*2048] bf16 pairs   (16 MB)
static constexpr size_t OFF_YR   = 16777216;   // u16[4096*4096] aliases X1B/W1B (32 MB)
static constexpr size_t OFF_SCAL = 83886080;   // 2x u32 (max|X1|, max|W1| float bits)

// ---------------- FWHT helpers ----------------
__device__ __forceinline__ void fwht16(float* v) {
#pragma unroll
  for (int b = 1; b < 16; b <<= 1) {
#pragma unroll
    for (int i = 0; i < 16; ++i) {
      if (!(i & b)) { float a = v[i]; float c = v[i | b]; v[i] = a + c; v[i | b] = a - c; }
    }
  }
}
__device__ __forceinline__ void fwht64(float* v) {
#pragma unroll
  for (int b = 1; b < 64; b <<= 1) {
#pragma unroll
    for (int i = 0; i < 64; ++i) {
      if (!(i & b)) { float a = v[i]; float c = v[i | b]; v[i] = a + c; v[i | b] = a - c; }
    }
  }
}

// ---------------- bf16 pack/unpack ----------------
__device__ __forceinline__ void unpack2(u32 u, float& a, float& b) {
  a = __uint_as_float(u << 16);
  b = __uint_as_float(u & 0xffff0000u);
}
__device__ __forceinline__ float bf16_f32(u16 h) {
  return __uint_as_float(((u32)h) << 16);
}
__device__ __forceinline__ u16 bf16_rne(float f) {
  u32 x = __float_as_uint(f);
  return (u16)(((x + 0x7fffu + ((x >> 16) & 1u)) >> 16) & 0xffffu);
}
__device__ __forceinline__ u32 pack2(float a, float b) {
  u32 x = __float_as_uint(a), y = __float_as_uint(b);
  u32 lo = ((x + 0x7fffu + ((x >> 16) & 1u)) >> 16) & 0xffffu;
  u32 hi = (y + 0x7fffu + ((y >> 16) & 1u)) & 0xffff0000u;
  return lo | hi;
}

// ---- x-path stage 1: H64 on consecutive 64-row groups, f32 -> bf16 (u16/col) ----
// 1 column/thread (was 2): grid 512 blocks -> 2 blocks/CU, ~half the VGPRs.
// u16-per-column layout is byte-identical to the old u32-pair layout.
__global__ __launch_bounds__(256) void xcol_s1(const float* __restrict__ x,
                                               u16* __restrict__ X1h,
                                               u32* __restrict__ scal) {
  if (blockIdx.x == 0 && blockIdx.y == 0 && threadIdx.x < 2) scal[threadIdx.x] = 0u;
  const int c = blockIdx.x * 256 + threadIdx.x;  // col 0..2047
  const int base = blockIdx.y * 64;
  float v[64];
#pragma unroll
  for (int r = 0; r < 64; ++r) v[r] = x[(size_t)(base + r) * 2048 + c];
  fwht64(v);
#pragma unroll
  for (int r = 0; r < 64; ++r)
    X1h[(size_t)(base + r) * 2048 + c] = bf16_rne(v[r]);
}

// ---- x-path stage 2: H64 on stride-64 rows, in-place bf16, + max. 1 col/thread ----
__global__ __launch_bounds__(256) void xcol_s2(u16* __restrict__ X1h,
                                               u32* __restrict__ gmax) {
  __shared__ float red[4];
  const int t = threadIdx.x;
  const int c = blockIdx.x * 256 + t;        // col 0..2047
  const int base = blockIdx.y;               // 0..63
  float v[64];
#pragma unroll
  for (int r = 0; r < 64; ++r)
    v[r] = bf16_f32(X1h[(size_t)(base + r * 64) * 2048 + c]);
  fwht64(v);
  float m = 0.f;
#pragma unroll
  for (int r = 0; r < 64; ++r) {
    X1h[(size_t)(base + r * 64) * 2048 + c] = bf16_rne(v[r]);
    m = fmaxf(m, fabsf(v[r]));
  }
#pragma unroll
  for (int off = 32; off > 0; off >>= 1) m = fmaxf(m, __shfl_down(m, off));
  if ((t & 63) == 0) red[t >> 6] = m;
  __syncthreads();
  if (t == 0) {
    m = fmaxf(fmaxf(red[0], red[1]), fmaxf(red[2], red[3]));
    atomicMax(gmax, __float_as_uint(m));
  }
}

// ---------------- w-path: full FWHT-4096 per row, f32 in -> bf16 out, + max --------
__global__ __launch_bounds__(256) void roww_fwht(const float* __restrict__ in,
                                                 u32* __restrict__ W1b,
                                                 u32* __restrict__ gmax) {
  __shared__ float s[4224];
  __shared__ float red[4];
  const int t = threadIdx.x;
  const size_t rowoff = (size_t)blockIdx.x * 4096;
  float v[16];
#pragma unroll
  for (int j = 0; j < 16; ++j) v[j] = in[rowoff + ((j << 8) | t)];
  fwht16(v);
#pragma unroll
  for (int j = 0; j < 16; ++j) { int e = (j << 8) | t; s[e + (e >> 5)] = v[j]; }
  __syncthreads();
#pragma unroll
  for (int j = 0; j < 16; ++j) { int e = ((t >> 4) << 8) | (j << 4) | (t & 15); v[j] = s[e + (e >> 5)]; }
  fwht16(v);
#pragma unroll
  for (int j = 0; j < 16; ++j) { int e = ((t >> 4) << 8) | (j << 4) | (t & 15); s[e + (e >> 5)] = v[j]; }
  __syncthreads();
#pragma unroll
  for (int j = 0; j < 16; ++j) { int e = (t << 4) | j; v[j] = s[e + (e >> 5)]; }
  fwht16(v);
  // store as bf16 pairs: cols t*16 .. t*16+15
  uint4 o0, o1;
  o0.x = pack2(v[0], v[1]);   o0.y = pack2(v[2], v[3]);
  o0.z = pack2(v[4], v[5]);   o0.w = pack2(v[6], v[7]);
  o1.x = pack2(v[8], v[9]);   o1.y = pack2(v[10], v[11]);
  o1.z = pack2(v[12], v[13]); o1.w = pack2(v[14], v[15]);
  uint4* op = (uint4*)(W1b + (size_t)blockIdx.x * 2048 + t * 8);
  op[0] = o0; op[1] = o1;
  float m = 0.f;
#pragma unroll
  for (int j = 0; j < 16; ++j) m = fmaxf(m, fabsf(v[j]));
#pragma unroll
  for (int off = 32; off > 0; off >>= 1) m = fmaxf(m, __shfl_down(m, off));
  if ((t & 63) == 0) red[t >> 6] = m;
  __syncthreads();
  if (t == 0) {
    m = fmaxf(fmaxf(red[0], red[1]), fmaxf(red[2], red[3]));
    atomicMax(gmax, __float_as_uint(m));
  }
}

// ---------------- Stochastic quantization ----------------
__device__ __forceinline__ float quant1(float X1, float nz, float s) {
  float xr = X1 * 0.015625f;         // /64, exact
  float xs = xr / s;
  float f  = floorf(xs);
  float q  = f + ((nz < (xs - f)) ? 1.0f : 0.0f);
  return fminf(fmaxf(q, -127.0f), 127.0f);
}
__device__ __forceinline__ u32 pk4(float a, float b, float c, float d) {
  return ((u32)(unsigned char)(char)(int)a)        |
         (((u32)(unsigned char)(char)(int)b) << 8) |
         (((u32)(unsigned char)(char)(int)c) << 16)|
         (((u32)(unsigned char)(char)(int)d) << 24);
}

__global__ __launch_bounds__(256) void quant_x_i8(const uint4* __restrict__ X1b,
                                                  const float4* __restrict__ nz,
                                                  uint2* __restrict__ qx,
                                                  const u32* __restrict__ scal) {
  size_t g = (size_t)blockIdx.x * 256 + threadIdx.x;
  float s = (__uint_as_float(scal[0]) * 0.015625f) / 127.0f;
  uint4 xv = X1b[g];
  float4 na = nz[2 * g], nb = nz[2 * g + 1];
  float a, b, c, d, e, f, gg, h;
  unpack2(xv.x, a, b);  unpack2(xv.y, c, d);
  unpack2(xv.z, e, f);  unpack2(xv.w, gg, h);
  u32 lo = pk4(quant1(a, na.x, s), quant1(b, na.y, s), quant1(c, na.z, s), quant1(d, na.w, s));
  u32 hi = pk4(quant1(e, nb.x, s), quant1(f, nb.y, s), quant1(gg, nb.z, s), quant1(h, nb.w, s));
  qx[g] = make_uint2(lo, hi);
}

// Quantize W1b [K,F] (bf16 pairs) and write transposed i8 [F,K].
__global__ __launch_bounds__(256) void quant_w_t_i8(const u32* __restrict__ W1b,
                                                    const float2* __restrict__ nz,
                                                    char* __restrict__ qwT,
                                                    const u32* __restrict__ scal) {
  __shared__ float tile[64][65];
  const int t = threadIdx.x;
  const int k0 = blockIdx.x * 64;   // over K=2048
  const int n0 = blockIdx.y * 64;   // over F=4096
  float s = (__uint_as_float(scal[1]) * 0.015625f) / 127.0f;
#pragma unroll
  for (int i = 0; i < 8; ++i) {
    int idx = t + 256 * i;          // 0..2047 over (k, np)
    int k = idx >> 5, np = idx & 31;
    u32 u = W1b[(size_t)(k0 + k) * 2048 + (n0 >> 1) + np];
    float2 nv = nz[(size_t)(k0 + k) * 2048 + (n0 >> 1) + np];
    float a, b; unpack2(u, a, b);
    tile[k][2 * np]     = quant1(a, nv.x, s);
    tile[k][2 * np + 1] = quant1(b, nv.y, s);
  }
  __syncthreads();
  const int kq = t & 15, nb = t >> 4;
#pragma unroll
  for (int i = 0; i < 4; ++i) {
    int n = nb + 16 * i;
    u32 p = pk4(tile[4 * kq + 0][n], tile[4 * kq + 1][n],
                tile[4 * kq + 2][n], tile[4 * kq + 3][n]);
    *(u32*)(qwT + (size_t)(n0 + n) * Kd + k0 + 4 * kq) = p;
  }
}

// ---------------- GEMM (i8 MFMA) + fused Rl/Cl output-rotation epilogue -------------
// Reverted to the verified 128^2-tile kernel (70.6 us). The 256^2 8-phase ports
// (R1-R3) all regressed: MFMA work is a constant ~13.4 us in every variant; the
// ports only added stall time (and scratch traffic: WRITE_SIZE 32768 -> 52224).
__device__ __forceinline__ void async16(const void* g, void* l) {
  __builtin_amdgcn_global_load_lds((__attribute__((address_space(1))) void*)(g),
                                   (__attribute__((address_space(3))) void*)(l),
                                   16, 0, 0);
}

__global__ __launch_bounds__(256) void gemm_i8(const char* __restrict__ A,   // [4096,2048] i8
                                               const char* __restrict__ Bt,  // [4096,2048] i8
                                               u16* __restrict__ C,          // [4096,4096] bf16
                                               const u32* __restrict__ scal) {
  __shared__ __align__(16) char As[128 * 128];
  __shared__ __align__(16) char Bs[128 * 128];
  const int t = threadIdx.x;
  const int w = t >> 6, l = t & 63;
  const int l15 = l & 15, quad = l >> 4;
  const int xorr = l15 & 7;
  // gm=8 panel swizzle for L2 locality (grid = 1024 1D)
  const int GM = 8, NN = 32, grp = GM * NN;
  int pid = blockIdx.x;
  int gid = pid / grp;
  int mm = gid * GM + (pid % GM);
  int nn = (pid % grp) / GM;
  const int m0 = mm * 128, n0 = nn * 128;
  const int mw = (w & 1) * 64, nw = (w >> 1) * 64;
  v4i acc[4][4] = {};

  // XOR source swizzle so LDS ds_read_b128 spreads over banks (R2: 0 conflicts)
  const int srow_lo = l >> 3;
  const int sbg = (l & 7) ^ ((l >> 3) & 7);

  for (int kg = 0; kg < Kd; kg += 128) {
#pragma unroll
    for (int i = 0; i < 4; ++i) {
      const int c = w * 4 + i;
      const int row = c * 8 + srow_lo;
      async16(A + (size_t)(m0 + row) * Kd + kg + sbg * 16, As + c * 1024);
      async16(Bt + (size_t)(n0 + row) * Kd + kg + sbg * 16, Bs + c * 1024);
    }
    __syncthreads();
#pragma unroll
    for (int kc = 0; kc < 2; ++kc) {
      v4i av[4], bv[4];
#pragma unroll
      for (int mi = 0; mi < 4; ++mi) {
        int row = mw + mi * 16 + l15;
        av[mi] = *(const v4i*)(As + row * 128 + (((kc * 4 + quad) ^ xorr) * 16));
      }
#pragma unroll
      for (int ni = 0; ni < 4; ++ni) {
        int row = nw + ni * 16 + l15;
        bv[ni] = *(const v4i*)(Bs + row * 128 + (((kc * 4 + quad) ^ xorr) * 16));
      }
#pragma unroll
      for (int mi = 0; mi < 4; ++mi)
#pragma unroll
        for (int ni = 0; ni < 4; ++ni)
          acc[mi][ni] = __builtin_amdgcn_mfma_i32_16x16x64_i8(av[mi], bv[ni], acc[mi][ni], 0, 0, 0);
    }
    __syncthreads();
  }
  float sx = (__uint_as_float(scal[0]) * 0.015625f) / 127.0f;
  float sw = (__uint_as_float(scal[1]) * 0.015625f) / 127.0f;
  float alpha = sx * sw * (1.0f / 4096.0f);

  // ---- fused epilogue: H64 over row-low bits (Rl) and col-low bits (Cl) ----
  // Wave quadrant = aligned 64x64 tile. row6 = mi*16+quad*4+r, col6 = ni*16+l15.
  // Register-resident bits {r, ni, mi} -> plain fwht64 over flat idx (order-free).
  // Lane-resident bits {l15: lane 0-3, quad: lane 4-5} -> 6 shfl_xor butterflies.
  float vals[64];
#pragma unroll
  for (int mi = 0; mi < 4; ++mi)
#pragma unroll
    for (int ni = 0; ni < 4; ++ni)
#pragma unroll
      for (int r = 0; r < 4; ++r)
        vals[mi * 16 + ni * 4 + r] = (float)acc[mi][ni][r] * alpha;
  fwht64(vals);
#pragma unroll
  for (int k = 0; k < 6; ++k) {
    const int mask = 1 << k;
    const int bit = (l >> k) & 1;
#pragma unroll
    for (int i = 0; i < 64; ++i) {
      float p = __shfl_xor(vals[i], mask, 64);
      vals[i] = bit ? (p - vals[i]) : (vals[i] + p);
    }
  }
#pragma unroll
  for (int mi = 0; mi < 4; ++mi)
#pragma unroll
    for (int ni = 0; ni < 4; ++ni)
#pragma unroll
      for (int r = 0; r < 4; ++r) {
        int row = m0 + mw + mi * 16 + quad * 4 + r;
        int col = n0 + nw + ni * 16 + l15;
        C[(size_t)row * Fd + col] = bf16_rne(vals[mi * 16 + ni * 4 + r]);
      }
}

// ---------------- Output pass Ch: H64 over col-high bits, per-row, bf16 in-place ----
__global__ __launch_bounds__(256) void colhigh_fwht(u16* __restrict__ yr) {
  __shared__ u16 sh[4 * 4096];   // 32768 B = 2048 uint4 -> 8 iters of 256 threads
  const int t = threadIdx.x;
  const size_t row0 = (size_t)blockIdx.x * 4;
  uint4* shv = (uint4*)sh;
  const uint4* g = (const uint4*)(yr + row0 * 4096);
#pragma unroll
  for (int i = 0; i < 8; ++i) shv[t + 256 * i] = g[t + 256 * i];
  __syncthreads();
  const int grp = t >> 6, cl = t & 63;
  const u16* shr = sh + grp * 4096;
  float v[64];
#pragma unroll
  for (int ch = 0; ch < 64; ++ch)
    v[ch] = __uint_as_float(((u32)shr[ch * 64 + cl]) << 16);
  fwht64(v);
  __syncthreads();
  u16* shw = sh + grp * 4096;
#pragma unroll
  for (int ch = 0; ch < 64; ++ch)
    shw[ch * 64 + cl] = bf16_rne(v[ch]);
  __syncthreads();
  uint4* go = (uint4*)(yr + row0 * 4096);
#pragma unroll
  for (int i = 0; i < 8; ++i) go[t + 256 * i] = shv[t + 256 * i];
}

// ---- Output pass Rh (LAST): H64 over stride-64 rows, +bias, f32 out. 1 col/thread --
__global__ __launch_bounds__(256, 1) void rowhigh_last(const u16* __restrict__ in,
                                                       float* __restrict__ outf,
                                                       const float* __restrict__ bias) {
  const int t = threadIdx.x;
  const int c = blockIdx.x * 256 + t;       // column 0..4095
  const int base = blockIdx.y;              // 0..63
  float v[64];
#pragma unroll
  for (int r = 0; r < 64; ++r)
    v[r] = bf16_f32(in[(size_t)(base + r * 64) * 4096 + c]);
  fwht64(v);
  float b0 = bias[c];
#pragma unroll
  for (int r = 0; r < 64; ++r)
    outf[(size_t)(base + r * 64) * 4096 + c] = v[r] + b0;
}

// ---------------- Launch ----------------
extern "C" void kernel_launch(void* const* d_in, const int* in_sizes, int n_in,
                              void* d_out, int out_size, void* d_ws, size_t ws_size,
                              hipStream_t stream) {
  (void)in_sizes; (void)n_in; (void)out_size; (void)ws_size;
  const float* x       = (const float*)d_in[0];  // [4096,2048]
  const float* w       = (const float*)d_in[1];  // [2048,4096]
  const float* bias    = (const float*)d_in[2];  // [4096]
  const float* noise_x = (const float*)d_in[5];  // [4096,2048]
  const float* noise_w = (const float*)d_in[6];  // [2048,4096]
  char* ws = (char*)d_ws;
  char* qx   = (char*)(ws + OFF_QX);
  char* qwT  = (char*)(ws + OFF_QWT);
  u16*  X1h  = (u16*) (ws + OFF_X1B);
  u32*  W1b  = (u32*) (ws + OFF_W1B);
  u16*  yr   = (u16*) (ws + OFF_YR);
  u32*  scal = (u32*) (ws + OFF_SCAL);
  float* out = (float*)d_out;

  // x rotation: H2 @ x (2 stages, bf16 intermediate); stage1 also zeroes scal
  xcol_s1<<<dim3(8, 64), dim3(256), 0, stream>>>(x, X1h, scal);
  xcol_s2<<<dim3(8, 64), dim3(256), 0, stream>>>(X1h, scal + 0);
  // w rotation: w @ H1 (row FWHT, bf16 out) + max
  roww_fwht<<<dim3(Kd), dim3(256), 0, stream>>>(w, W1b, scal + 1);
  // stochastic int8 quantization
  quant_x_i8<<<dim3(4096), dim3(256), 0, stream>>>(
      (const uint4*)X1h, (const float4*)noise_x, (uint2*)qx, scal);
  quant_w_t_i8<<<dim3(Kd / 64, Fd / 64), dim3(256), 0, stream>>>(
      W1b, (const float2*)noise_w, qwT, scal);
  // core i8 GEMM -> yr bf16 with fused Rl/Cl output rotation
  gemm_i8<<<dim3((Bd / 128) * (Fd / 128)), dim3(256), 0, stream>>>(qx, qwT, yr, scal);
  // remaining output stages: col-high, then row-high (+bias, f32)
  colhigh_fwht<<<dim3(Bd / 4), dim3(256), 0, stream>>>(yr);
  rowhigh_last<<<dim3(16, 64), dim3(256), 0, stream>>>(yr, out, bias);
}

// Round 6
// 356.850 us; speedup vs baseline: 1.3253x; 1.0148x over previous
//
#include <hip/hip_runtime.h>
#include <stdint.h>

typedef unsigned short u16;
typedef unsigned int   u32;
typedef int v4i __attribute__((ext_vector_type(4)));

static constexpr int Bd = 4096;   // batch
static constexpr int Kd = 2048;   // in-features (GEMM K)
static constexpr int Fd = 4096;   // out-features

// Workspace (bytes). yr aliases X1B+W1B (dead before GEMM writes).
static constexpr size_t OFF_QX   = 0;          // i8 [4096*2048]              (8 MB)
static constexpr size_t OFF_QWT  = 8388608;    // i8 [4096*2048] transposed   (8 MB)
static constexpr size_t OFF_X1B  = 16777216;   // u16[4096*2048] bf16         (16 MB)
static constexpr size_t OFF_W1B  = 33554432;   // u32[2048*2048] bf16 pairs   (16 MB)
static constexpr size_t OFF_YR   = 16777216;   // u16[4096*4096] aliases X1B/W1B (32 MB)
static constexpr size_t OFF_SCAL = 83886080;   // 2x u32 (max|X1|, max|W1| float bits)

// ---------------- FWHT helpers ----------------
__device__ __forceinline__ void fwht16(float* v) {
#pragma unroll
  for (int b = 1; b < 16; b <<= 1) {
#pragma unroll
    for (int i = 0; i < 16; ++i) {
      if (!(i & b)) { float a = v[i]; float c = v[i | b]; v[i] = a + c; v[i | b] = a - c; }
    }
  }
}
__device__ __forceinline__ void fwht64(float* v) {
#pragma unroll
  for (int b = 1; b < 64; b <<= 1) {
#pragma unroll
    for (int i = 0; i < 64; ++i) {
      if (!(i & b)) { float a = v[i]; float c = v[i | b]; v[i] = a + c; v[i | b] = a - c; }
    }
  }
}

// ---------------- bf16 pack/unpack ----------------
__device__ __forceinline__ void unpack2(u32 u, float& a, float& b) {
  a = __uint_as_float(u << 16);
  b = __uint_as_float(u & 0xffff0000u);
}
__device__ __forceinline__ float bf16_f32(u16 h) {
  return __uint_as_float(((u32)h) << 16);
}
__device__ __forceinline__ u16 bf16_rne(float f) {
  u32 x = __float_as_uint(f);
  return (u16)(((x + 0x7fffu + ((x >> 16) & 1u)) >> 16) & 0xffffu);
}
__device__ __forceinline__ u32 pack2(float a, float b) {
  u32 x = __float_as_uint(a), y = __float_as_uint(b);
  u32 lo = ((x + 0x7fffu + ((x >> 16) & 1u)) >> 16) & 0xffffu;
  u32 hi = (y + 0x7fffu + ((y >> 16) & 1u)) & 0xffff0000u;
  return lo | hi;
}

// ---- x-path stage 1: H64 on consecutive 64-row groups, f32 -> bf16 (u16/col) ----
__global__ __launch_bounds__(256) void xcol_s1(const float* __restrict__ x,
                                               u16* __restrict__ X1h,
                                               u32* __restrict__ scal) {
  if (blockIdx.x == 0 && blockIdx.y == 0 && threadIdx.x < 2) scal[threadIdx.x] = 0u;
  const int c = blockIdx.x * 256 + threadIdx.x;  // col 0..2047
  const int base = blockIdx.y * 64;
  float v[64];
#pragma unroll
  for (int r = 0; r < 64; ++r) v[r] = x[(size_t)(base + r) * 2048 + c];
  fwht64(v);
#pragma unroll
  for (int r = 0; r < 64; ++r)
    X1h[(size_t)(base + r) * 2048 + c] = bf16_rne(v[r]);
}

// ---- x-path stage 2: H64 on stride-64 rows, in-place bf16, + max ----
// LDS-staged loads (G13): 64 strided rows x 256 cols tile, uint4 global reads
// (16B/lane) instead of scalar u16 (2B/lane). FP order per column unchanged.
__global__ __launch_bounds__(256) void xcol_s2(u16* __restrict__ X1h,
                                               u32* __restrict__ gmax) {
  __shared__ u16 tile[64 * 264];   // row stride 264 u16 (+8 pad) -> spread banks
  __shared__ float red[4];
  const int t = threadIdx.x;
  const int c0 = blockIdx.x * 256;           // col chunk base (grid.x = 8)
  const int base = blockIdx.y;               // 0..63
#pragma unroll
  for (int i = 0; i < 8; ++i) {
    int idx = t + 256 * i;                   // 0..2047
    int r = idx >> 5, u = idx & 31;
    uint4 d = *(const uint4*)(X1h + (size_t)(base + r * 64) * 2048 + c0 + u * 8);
    *(uint4*)(&tile[r * 264 + u * 8]) = d;
  }
  __syncthreads();
  float v[64];
#pragma unroll
  for (int r = 0; r < 64; ++r) v[r] = bf16_f32(tile[r * 264 + t]);
  fwht64(v);
  float m = 0.f;
  const int c = c0 + t;
#pragma unroll
  for (int r = 0; r < 64; ++r) {
    X1h[(size_t)(base + r * 64) * 2048 + c] = bf16_rne(v[r]);
    m = fmaxf(m, fabsf(v[r]));
  }
#pragma unroll
  for (int off = 32; off > 0; off >>= 1) m = fmaxf(m, __shfl_down(m, off));
  if ((t & 63) == 0) red[t >> 6] = m;
  __syncthreads();
  if (t == 0) {
    m = fmaxf(fmaxf(red[0], red[1]), fmaxf(red[2], red[3]));
    atomicMax(gmax, __float_as_uint(m));
  }
}

// ---------------- w-path: full FWHT-4096 per row, f32 in -> bf16 out, + max --------
__global__ __launch_bounds__(256) void roww_fwht(const float* __restrict__ in,
                                                 u32* __restrict__ W1b,
                                                 u32* __restrict__ gmax) {
  __shared__ float s[4224];
  __shared__ float red[4];
  const int t = threadIdx.x;
  const size_t rowoff = (size_t)blockIdx.x * 4096;
  float v[16];
#pragma unroll
  for (int j = 0; j < 16; ++j) v[j] = in[rowoff + ((j << 8) | t)];
  fwht16(v);
#pragma unroll
  for (int j = 0; j < 16; ++j) { int e = (j << 8) | t; s[e + (e >> 5)] = v[j]; }
  __syncthreads();
#pragma unroll
  for (int j = 0; j < 16; ++j) { int e = ((t >> 4) << 8) | (j << 4) | (t & 15); v[j] = s[e + (e >> 5)]; }
  fwht16(v);
#pragma unroll
  for (int j = 0; j < 16; ++j) { int e = ((t >> 4) << 8) | (j << 4) | (t & 15); s[e + (e >> 5)] = v[j]; }
  __syncthreads();
#pragma unroll
  for (int j = 0; j < 16; ++j) { int e = (t << 4) | j; v[j] = s[e + (e >> 5)]; }
  fwht16(v);
  // store as bf16 pairs: cols t*16 .. t*16+15
  uint4 o0, o1;
  o0.x = pack2(v[0], v[1]);   o0.y = pack2(v[2], v[3]);
  o0.z = pack2(v[4], v[5]);   o0.w = pack2(v[6], v[7]);
  o1.x = pack2(v[8], v[9]);   o1.y = pack2(v[10], v[11]);
  o1.z = pack2(v[12], v[13]); o1.w = pack2(v[14], v[15]);
  uint4* op = (uint4*)(W1b + (size_t)blockIdx.x * 2048 + t * 8);
  op[0] = o0; op[1] = o1;
  float m = 0.f;
#pragma unroll
  for (int j = 0; j < 16; ++j) m = fmaxf(m, fabsf(v[j]));
#pragma unroll
  for (int off = 32; off > 0; off >>= 1) m = fmaxf(m, __shfl_down(m, off));
  if ((t & 63) == 0) red[t >> 6] = m;
  __syncthreads();
  if (t == 0) {
    m = fmaxf(fmaxf(red[0], red[1]), fmaxf(red[2], red[3]));
    atomicMax(gmax, __float_as_uint(m));
  }
}

// ---------------- Stochastic quantization ----------------
__device__ __forceinline__ float quant1(float X1, float nz, float s) {
  float xr = X1 * 0.015625f;         // /64, exact
  float xs = xr / s;
  float f  = floorf(xs);
  float q  = f + ((nz < (xs - f)) ? 1.0f : 0.0f);
  return fminf(fmaxf(q, -127.0f), 127.0f);
}
__device__ __forceinline__ u32 pk4(float a, float b, float c, float d) {
  return ((u32)(unsigned char)(char)(int)a)        |
         (((u32)(unsigned char)(char)(int)b) << 8) |
         (((u32)(unsigned char)(char)(int)c) << 16)|
         (((u32)(unsigned char)(char)(int)d) << 24);
}

__global__ __launch_bounds__(256) void quant_x_i8(const uint4* __restrict__ X1b,
                                                  const float4* __restrict__ nz,
                                                  uint2* __restrict__ qx,
                                                  const u32* __restrict__ scal) {
  size_t g = (size_t)blockIdx.x * 256 + threadIdx.x;
  float s = (__uint_as_float(scal[0]) * 0.015625f) / 127.0f;
  uint4 xv = X1b[g];
  float4 na = nz[2 * g], nb = nz[2 * g + 1];
  float a, b, c, d, e, f, gg, h;
  unpack2(xv.x, a, b);  unpack2(xv.y, c, d);
  unpack2(xv.z, e, f);  unpack2(xv.w, gg, h);
  u32 lo = pk4(quant1(a, na.x, s), quant1(b, na.y, s), quant1(c, na.z, s), quant1(d, na.w, s));
  u32 hi = pk4(quant1(e, nb.x, s), quant1(f, nb.y, s), quant1(gg, nb.z, s), quant1(h, nb.w, s));
  qx[g] = make_uint2(lo, hi);
}

// Quantize W1b [K,F] (bf16 pairs) and write transposed i8 [F,K].
__global__ __launch_bounds__(256) void quant_w_t_i8(const u32* __restrict__ W1b,
                                                    const float2* __restrict__ nz,
                                                    char* __restrict__ qwT,
                                                    const u32* __restrict__ scal) {
  __shared__ float tile[64][65];
  const int t = threadIdx.x;
  const int k0 = blockIdx.x * 64;   // over K=2048
  const int n0 = blockIdx.y * 64;   // over F=4096
  float s = (__uint_as_float(scal[1]) * 0.015625f) / 127.0f;
#pragma unroll
  for (int i = 0; i < 8; ++i) {
    int idx = t + 256 * i;          // 0..2047 over (k, np)
    int k = idx >> 5, np = idx & 31;
    u32 u = W1b[(size_t)(k0 + k) * 2048 + (n0 >> 1) + np];
    float2 nv = nz[(size_t)(k0 + k) * 2048 + (n0 >> 1) + np];
    float a, b; unpack2(u, a, b);
    tile[k][2 * np]     = quant1(a, nv.x, s);
    tile[k][2 * np + 1] = quant1(b, nv.y, s);
  }
  __syncthreads();
  const int kq = t & 15, nb = t >> 4;
#pragma unroll
  for (int i = 0; i < 4; ++i) {
    int n = nb + 16 * i;
    u32 p = pk4(tile[4 * kq + 0][n], tile[4 * kq + 1][n],
                tile[4 * kq + 2][n], tile[4 * kq + 3][n]);
    *(u32*)(qwT + (size_t)(n0 + n) * Kd + k0 + 4 * kq) = p;
  }
}

// ---------------- GEMM (i8 MFMA) + fused Rl/Cl output-rotation epilogue -------------
// Verified 128^2-tile kernel (70.6 us). The 256^2 8-phase ports (R1-R3) all
// regressed: MFMA work is a constant ~13.4 us in every variant; the ports only
// added stall time (and scratch traffic: WRITE_SIZE 32768 -> 52224).
__device__ __forceinline__ void async16(const void* g, void* l) {
  __builtin_amdgcn_global_load_lds((__attribute__((address_space(1))) void*)(g),
                                   (__attribute__((address_space(3))) void*)(l),
                                   16, 0, 0);
}

__global__ __launch_bounds__(256) void gemm_i8(const char* __restrict__ A,   // [4096,2048] i8
                                               const char* __restrict__ Bt,  // [4096,2048] i8
                                               u16* __restrict__ C,          // [4096,4096] bf16
                                               const u32* __restrict__ scal) {
  __shared__ __align__(16) char As[128 * 128];
  __shared__ __align__(16) char Bs[128 * 128];
  const int t = threadIdx.x;
  const int w = t >> 6, l = t & 63;
  const int l15 = l & 15, quad = l >> 4;
  const int xorr = l15 & 7;
  // gm=8 panel swizzle for L2 locality (grid = 1024 1D)
  const int GM = 8, NN = 32, grp = GM * NN;
  int pid = blockIdx.x;
  int gid = pid / grp;
  int mm = gid * GM + (pid % GM);
  int nn = (pid % grp) / GM;
  const int m0 = mm * 128, n0 = nn * 128;
  const int mw = (w & 1) * 64, nw = (w >> 1) * 64;
  v4i acc[4][4] = {};

  // XOR source swizzle so LDS ds_read_b128 spreads over banks (R2: 0 conflicts)
  const int srow_lo = l >> 3;
  const int sbg = (l & 7) ^ ((l >> 3) & 7);

  for (int kg = 0; kg < Kd; kg += 128) {
#pragma unroll
    for (int i = 0; i < 4; ++i) {
      const int c = w * 4 + i;
      const int row = c * 8 + srow_lo;
      async16(A + (size_t)(m0 + row) * Kd + kg + sbg * 16, As + c * 1024);
      async16(Bt + (size_t)(n0 + row) * Kd + kg + sbg * 16, Bs + c * 1024);
    }
    __syncthreads();
#pragma unroll
    for (int kc = 0; kc < 2; ++kc) {
      v4i av[4], bv[4];
#pragma unroll
      for (int mi = 0; mi < 4; ++mi) {
        int row = mw + mi * 16 + l15;
        av[mi] = *(const v4i*)(As + row * 128 + (((kc * 4 + quad) ^ xorr) * 16));
      }
#pragma unroll
      for (int ni = 0; ni < 4; ++ni) {
        int row = nw + ni * 16 + l15;
        bv[ni] = *(const v4i*)(Bs + row * 128 + (((kc * 4 + quad) ^ xorr) * 16));
      }
#pragma unroll
      for (int mi = 0; mi < 4; ++mi)
#pragma unroll
        for (int ni = 0; ni < 4; ++ni)
          acc[mi][ni] = __builtin_amdgcn_mfma_i32_16x16x64_i8(av[mi], bv[ni], acc[mi][ni], 0, 0, 0);
    }
    __syncthreads();
  }
  float sx = (__uint_as_float(scal[0]) * 0.015625f) / 127.0f;
  float sw = (__uint_as_float(scal[1]) * 0.015625f) / 127.0f;
  float alpha = sx * sw * (1.0f / 4096.0f);

  // ---- fused epilogue: H64 over row-low bits (Rl) and col-low bits (Cl) ----
  // Wave quadrant = aligned 64x64 tile. row6 = mi*16+quad*4+r, col6 = ni*16+l15.
  // Register-resident bits {r, ni, mi} -> plain fwht64 over flat idx (order-free).
  // Lane-resident bits {l15: lane 0-3, quad: lane 4-5} -> 6 shfl_xor butterflies.
  float vals[64];
#pragma unroll
  for (int mi = 0; mi < 4; ++mi)
#pragma unroll
    for (int ni = 0; ni < 4; ++ni)
#pragma unroll
      for (int r = 0; r < 4; ++r)
        vals[mi * 16 + ni * 4 + r] = (float)acc[mi][ni][r] * alpha;
  fwht64(vals);
#pragma unroll
  for (int k = 0; k < 6; ++k) {
    const int mask = 1 << k;
    const int bit = (l >> k) & 1;
#pragma unroll
    for (int i = 0; i < 64; ++i) {
      float p = __shfl_xor(vals[i], mask, 64);
      vals[i] = bit ? (p - vals[i]) : (vals[i] + p);
    }
  }
#pragma unroll
  for (int mi = 0; mi < 4; ++mi)
#pragma unroll
    for (int ni = 0; ni < 4; ++ni)
#pragma unroll
      for (int r = 0; r < 4; ++r) {
        int row = m0 + mw + mi * 16 + quad * 4 + r;
        int col = n0 + nw + ni * 16 + l15;
        C[(size_t)row * Fd + col] = bf16_rne(vals[mi * 16 + ni * 4 + r]);
      }
}

// ---------------- Output pass Ch: H64 over col-high bits, per-row, bf16 in-place ----
__global__ __launch_bounds__(256) void colhigh_fwht(u16* __restrict__ yr) {
  __shared__ u16 sh[4 * 4096];   // 32768 B = 2048 uint4 -> 8 iters of 256 threads
  const int t = threadIdx.x;
  const size_t row0 = (size_t)blockIdx.x * 4;
  uint4* shv = (uint4*)sh;
  const uint4* g = (const uint4*)(yr + row0 * 4096);
#pragma unroll
  for (int i = 0; i < 8; ++i) shv[t + 256 * i] = g[t + 256 * i];
  __syncthreads();
  const int grp = t >> 6, cl = t & 63;
  const u16* shr = sh + grp * 4096;
  float v[64];
#pragma unroll
  for (int ch = 0; ch < 64; ++ch)
    v[ch] = __uint_as_float(((u32)shr[ch * 64 + cl]) << 16);
  fwht64(v);
  __syncthreads();
  u16* shw = sh + grp * 4096;
#pragma unroll
  for (int ch = 0; ch < 64; ++ch)
    shw[ch * 64 + cl] = bf16_rne(v[ch]);
  __syncthreads();
  uint4* go = (uint4*)(yr + row0 * 4096);
#pragma unroll
  for (int i = 0; i < 8; ++i) go[t + 256 * i] = shv[t + 256 * i];
}

// ---- Output pass Rh (LAST): H64 over stride-64 rows, +bias, f32 out ----
// LDS-staged loads (G13): uint4 global reads instead of scalar u16.
__global__ __launch_bounds__(256) void rowhigh_last(const u16* __restrict__ in,
                                                    float* __restrict__ outf,
                                                    const float* __restrict__ bias) {
  __shared__ u16 tile[64 * 264];   // 64 rows x 256 cols, +8 u16 pad per row
  const int t = threadIdx.x;
  const int c0 = blockIdx.x * 256;          // col chunk base (grid.x = 16)
  const int base = blockIdx.y;              // 0..63
#pragma unroll
  for (int i = 0; i < 8; ++i) {
    int idx = t + 256 * i;                  // 0..2047
    int r = idx >> 5, u = idx & 31;
    uint4 d = *(const uint4*)(in + (size_t)(base + r * 64) * 4096 + c0 + u * 8);
    *(uint4*)(&tile[r * 264 + u * 8]) = d;
  }
  __syncthreads();
  float v[64];
#pragma unroll
  for (int r = 0; r < 64; ++r) v[r] = bf16_f32(tile[r * 264 + t]);
  fwht64(v);
  const int c = c0 + t;
  float b0 = bias[c];
#pragma unroll
  for (int r = 0; r < 64; ++r)
    outf[(size_t)(base + r * 64) * 4096 + c] = v[r] + b0;
}

// ---------------- Launch ----------------
extern "C" void kernel_launch(void* const* d_in, const int* in_sizes, int n_in,
                              void* d_out, int out_size, void* d_ws, size_t ws_size,
                              hipStream_t stream) {
  (void)in_sizes; (void)n_in; (void)out_size; (void)ws_size;
  const float* x       = (const float*)d_in[0];  // [4096,2048]
  const float* w       = (const float*)d_in[1];  // [2048,4096]
  const float* bias    = (const float*)d_in[2];  // [4096]
  const float* noise_x = (const float*)d_in[5];  // [4096,2048]
  const float* noise_w = (const float*)d_in[6];  // [2048,4096]
  char* ws = (char*)d_ws;
  char* qx   = (char*)(ws + OFF_QX);
  char* qwT  = (char*)(ws + OFF_QWT);
  u16*  X1h  = (u16*) (ws + OFF_X1B);
  u32*  W1b  = (u32*) (ws + OFF_W1B);
  u16*  yr   = (u16*) (ws + OFF_YR);
  u32*  scal = (u32*) (ws + OFF_SCAL);
  float* out = (float*)d_out;

  // x rotation: H2 @ x (2 stages, bf16 intermediate); stage1 also zeroes scal
  xcol_s1<<<dim3(8, 64), dim3(256), 0, stream>>>(x, X1h, scal);
  xcol_s2<<<dim3(8, 64), dim3(256), 0, stream>>>(X1h, scal + 0);
  // w rotation: w @ H1 (row FWHT, bf16 out) + max
  roww_fwht<<<dim3(Kd), dim3(256), 0, stream>>>(w, W1b, scal + 1);
  // stochastic int8 quantization
  quant_x_i8<<<dim3(4096), dim3(256), 0, stream>>>(
      (const uint4*)X1h, (const float4*)noise_x, (uint2*)qx, scal);
  quant_w_t_i8<<<dim3(Kd / 64, Fd / 64), dim3(256), 0, stream>>>(
      W1b, (const float2*)noise_w, qwT, scal);
  // core i8 GEMM -> yr bf16 with fused Rl/Cl output rotation
  gemm_i8<<<dim3((Bd / 128) * (Fd / 128)), dim3(256), 0, stream>>>(qx, qwT, yr, scal);
  // remaining output stages: col-high, then row-high (+bias, f32)
  colhigh_fwht<<<dim3(Bd / 4), dim3(256), 0, stream>>>(yr);
  rowhigh_last<<<dim3(16, 64), dim3(256), 0, stream>>>(yr, out, bias);
}

// Round 7
// 353.924 us; speedup vs baseline: 1.3363x; 1.0083x over previous
//
#include <hip/hip_runtime.h>
#include <stdint.h>

typedef unsigned short u16;
typedef unsigned int   u32;
typedef int v4i __attribute__((ext_vector_type(4)));

static constexpr int Bd = 4096;   // batch
static constexpr int Kd = 2048;   // in-features (GEMM K)
static constexpr int Fd = 4096;   // out-features

// Workspace (bytes). yr aliases X1B+W1B (dead before GEMM writes).
static constexpr size_t OFF_QX   = 0;          // i8 [4096*2048]              (8 MB)
static constexpr size_t OFF_QWT  = 8388608;    // i8 [4096*2048] transposed   (8 MB)
static constexpr size_t OFF_X1B  = 16777216;   // u16[4096*2048] bf16         (16 MB)
static constexpr size_t OFF_W1B  = 33554432;   // u32[2048*2048] bf16 pairs   (16 MB)
static constexpr size_t OFF_YR   = 16777216;   // u16[4096*4096] aliases X1B/W1B (32 MB)
static constexpr size_t OFF_SCAL = 83886080;   // 2x u32 (max|X1|, max|W1| float bits)

// ---------------- FWHT helpers ----------------
__device__ __forceinline__ void fwht16(float* v) {
#pragma unroll
  for (int b = 1; b < 16; b <<= 1) {
#pragma unroll
    for (int i = 0; i < 16; ++i) {
      if (!(i & b)) { float a = v[i]; float c = v[i | b]; v[i] = a + c; v[i | b] = a - c; }
    }
  }
}
__device__ __forceinline__ void fwht64(float* v) {
#pragma unroll
  for (int b = 1; b < 64; b <<= 1) {
#pragma unroll
    for (int i = 0; i < 64; ++i) {
      if (!(i & b)) { float a = v[i]; float c = v[i | b]; v[i] = a + c; v[i | b] = a - c; }
    }
  }
}

// ---------------- bf16 pack/unpack ----------------
__device__ __forceinline__ void unpack2(u32 u, float& a, float& b) {
  a = __uint_as_float(u << 16);
  b = __uint_as_float(u & 0xffff0000u);
}
__device__ __forceinline__ float bf16_f32(u16 h) {
  return __uint_as_float(((u32)h) << 16);
}
__device__ __forceinline__ u16 bf16_rne(float f) {
  u32 x = __float_as_uint(f);
  return (u16)(((x + 0x7fffu + ((x >> 16) & 1u)) >> 16) & 0xffffu);
}
__device__ __forceinline__ u32 pack2(float a, float b) {
  u32 x = __float_as_uint(a), y = __float_as_uint(b);
  u32 lo = ((x + 0x7fffu + ((x >> 16) & 1u)) >> 16) & 0xffffu;
  u32 hi = (y + 0x7fffu + ((y >> 16) & 1u)) & 0xffff0000u;
  return lo | hi;
}

// ---- x-path stage 1: H64 on consecutive 64-row groups, f32 -> bf16 (u16/col) ----
__global__ __launch_bounds__(256) void xcol_s1(const float* __restrict__ x,
                                               u16* __restrict__ X1h,
                                               u32* __restrict__ scal) {
  if (blockIdx.x == 0 && blockIdx.y == 0 && threadIdx.x < 2) scal[threadIdx.x] = 0u;
  const int c = blockIdx.x * 256 + threadIdx.x;  // col 0..2047
  const int base = blockIdx.y * 64;
  float v[64];
#pragma unroll
  for (int r = 0; r < 64; ++r) v[r] = x[(size_t)(base + r) * 2048 + c];
  fwht64(v);
#pragma unroll
  for (int r = 0; r < 64; ++r)
    X1h[(size_t)(base + r) * 2048 + c] = bf16_rne(v[r]);
}

// ---- x-path stage 2: H64 on stride-64 rows, in-place bf16, + max ----
// LDS-staged loads (G13): 64 strided rows x 256 cols tile, uint4 global reads
// (16B/lane) instead of scalar u16 (2B/lane). FP order per column unchanged.
__global__ __launch_bounds__(256) void xcol_s2(u16* __restrict__ X1h,
                                               u32* __restrict__ gmax) {
  __shared__ u16 tile[64 * 264];   // row stride 264 u16 (+8 pad) -> spread banks
  __shared__ float red[4];
  const int t = threadIdx.x;
  const int c0 = blockIdx.x * 256;           // col chunk base (grid.x = 8)
  const int base = blockIdx.y;               // 0..63
#pragma unroll
  for (int i = 0; i < 8; ++i) {
    int idx = t + 256 * i;                   // 0..2047
    int r = idx >> 5, u = idx & 31;
    uint4 d = *(const uint4*)(X1h + (size_t)(base + r * 64) * 2048 + c0 + u * 8);
    *(uint4*)(&tile[r * 264 + u * 8]) = d;
  }
  __syncthreads();
  float v[64];
#pragma unroll
  for (int r = 0; r < 64; ++r) v[r] = bf16_f32(tile[r * 264 + t]);
  fwht64(v);
  float m = 0.f;
  const int c = c0 + t;
#pragma unroll
  for (int r = 0; r < 64; ++r) {
    X1h[(size_t)(base + r * 64) * 2048 + c] = bf16_rne(v[r]);
    m = fmaxf(m, fabsf(v[r]));
  }
#pragma unroll
  for (int off = 32; off > 0; off >>= 1) m = fmaxf(m, __shfl_down(m, off));
  if ((t & 63) == 0) red[t >> 6] = m;
  __syncthreads();
  if (t == 0) {
    m = fmaxf(fmaxf(red[0], red[1]), fmaxf(red[2], red[3]));
    atomicMax(gmax, __float_as_uint(m));
  }
}

// ---------------- w-path: full FWHT-4096 per row, f32 in -> bf16 out, + max --------
__global__ __launch_bounds__(256) void roww_fwht(const float* __restrict__ in,
                                                 u32* __restrict__ W1b,
                                                 u32* __restrict__ gmax) {
  __shared__ float s[4224];
  __shared__ float red[4];
  const int t = threadIdx.x;
  const size_t rowoff = (size_t)blockIdx.x * 4096;
  float v[16];
#pragma unroll
  for (int j = 0; j < 16; ++j) v[j] = in[rowoff + ((j << 8) | t)];
  fwht16(v);
#pragma unroll
  for (int j = 0; j < 16; ++j) { int e = (j << 8) | t; s[e + (e >> 5)] = v[j]; }
  __syncthreads();
#pragma unroll
  for (int j = 0; j < 16; ++j) { int e = ((t >> 4) << 8) | (j << 4) | (t & 15); v[j] = s[e + (e >> 5)]; }
  fwht16(v);
#pragma unroll
  for (int j = 0; j < 16; ++j) { int e = ((t >> 4) << 8) | (j << 4) | (t & 15); s[e + (e >> 5)] = v[j]; }
  __syncthreads();
#pragma unroll
  for (int j = 0; j < 16; ++j) { int e = (t << 4) | j; v[j] = s[e + (e >> 5)]; }
  fwht16(v);
  // store as bf16 pairs: cols t*16 .. t*16+15
  uint4 o0, o1;
  o0.x = pack2(v[0], v[1]);   o0.y = pack2(v[2], v[3]);
  o0.z = pack2(v[4], v[5]);   o0.w = pack2(v[6], v[7]);
  o1.x = pack2(v[8], v[9]);   o1.y = pack2(v[10], v[11]);
  o1.z = pack2(v[12], v[13]); o1.w = pack2(v[14], v[15]);
  uint4* op = (uint4*)(W1b + (size_t)blockIdx.x * 2048 + t * 8);
  op[0] = o0; op[1] = o1;
  float m = 0.f;
#pragma unroll
  for (int j = 0; j < 16; ++j) m = fmaxf(m, fabsf(v[j]));
#pragma unroll
  for (int off = 32; off > 0; off >>= 1) m = fmaxf(m, __shfl_down(m, off));
  if ((t & 63) == 0) red[t >> 6] = m;
  __syncthreads();
  if (t == 0) {
    m = fmaxf(fmaxf(red[0], red[1]), fmaxf(red[2], red[3]));
    atomicMax(gmax, __float_as_uint(m));
  }
}

// ---------------- Stochastic quantization ----------------
__device__ __forceinline__ float quant1(float X1, float nz, float s) {
  float xr = X1 * 0.015625f;         // /64, exact
  float xs = xr / s;
  float f  = floorf(xs);
  float q  = f + ((nz < (xs - f)) ? 1.0f : 0.0f);
  return fminf(fmaxf(q, -127.0f), 127.0f);
}
__device__ __forceinline__ u32 pk4(float a, float b, float c, float d) {
  return ((u32)(unsigned char)(char)(int)a)        |
         (((u32)(unsigned char)(char)(int)b) << 8) |
         (((u32)(unsigned char)(char)(int)c) << 16)|
         (((u32)(unsigned char)(char)(int)d) << 24);
}

__global__ __launch_bounds__(256) void quant_x_i8(const uint4* __restrict__ X1b,
                                                  const float4* __restrict__ nz,
                                                  uint2* __restrict__ qx,
                                                  const u32* __restrict__ scal) {
  size_t g = (size_t)blockIdx.x * 256 + threadIdx.x;
  float s = (__uint_as_float(scal[0]) * 0.015625f) / 127.0f;
  uint4 xv = X1b[g];
  float4 na = nz[2 * g], nb = nz[2 * g + 1];
  float a, b, c, d, e, f, gg, h;
  unpack2(xv.x, a, b);  unpack2(xv.y, c, d);
  unpack2(xv.z, e, f);  unpack2(xv.w, gg, h);
  u32 lo = pk4(quant1(a, na.x, s), quant1(b, na.y, s), quant1(c, na.z, s), quant1(d, na.w, s));
  u32 hi = pk4(quant1(e, nb.x, s), quant1(f, nb.y, s), quant1(gg, nb.z, s), quant1(h, nb.w, s));
  qx[g] = make_uint2(lo, hi);
}

// Quantize W1b [K,F] (bf16 pairs) and write transposed i8 [F,K].
__global__ __launch_bounds__(256) void quant_w_t_i8(const u32* __restrict__ W1b,
                                                    const float2* __restrict__ nz,
                                                    char* __restrict__ qwT,
                                                    const u32* __restrict__ scal) {
  __shared__ float tile[64][65];
  const int t = threadIdx.x;
  const int k0 = blockIdx.x * 64;   // over K=2048
  const int n0 = blockIdx.y * 64;   // over F=4096
  float s = (__uint_as_float(scal[1]) * 0.015625f) / 127.0f;
#pragma unroll
  for (int i = 0; i < 8; ++i) {
    int idx = t + 256 * i;          // 0..2047 over (k, np)
    int k = idx >> 5, np = idx & 31;
    u32 u = W1b[(size_t)(k0 + k) * 2048 + (n0 >> 1) + np];
    float2 nv = nz[(size_t)(k0 + k) * 2048 + (n0 >> 1) + np];
    float a, b; unpack2(u, a, b);
    tile[k][2 * np]     = quant1(a, nv.x, s);
    tile[k][2 * np + 1] = quant1(b, nv.y, s);
  }
  __syncthreads();
  const int kq = t & 15, nb = t >> 4;
#pragma unroll
  for (int i = 0; i < 4; ++i) {
    int n = nb + 16 * i;
    u32 p = pk4(tile[4 * kq + 0][n], tile[4 * kq + 1][n],
                tile[4 * kq + 2][n], tile[4 * kq + 3][n]);
    *(u32*)(qwT + (size_t)(n0 + n) * Kd + k0 + 4 * kq) = p;
  }
}

// ---------------- GEMM (i8 MFMA) + fused Rl/Cl output-rotation epilogue -------------
// 128^2 tile + minimal 2-phase LDS double-buffer (T3 "minimum 2-phase"): stage
// tile k+1 while computing tile k; single barrier per K-tile. R6 showed the old
// stage->drain->compute structure fully exposes HBM latency per K-tile (gemm
// 70.5 vs 98 us with identical code across benches = latency-fragile).
__device__ __forceinline__ void async16(const void* g, void* l) {
  __builtin_amdgcn_global_load_lds((__attribute__((address_space(1))) void*)(g),
                                   (__attribute__((address_space(3))) void*)(l),
                                   16, 0, 0);
}

__global__ __launch_bounds__(256) void gemm_i8(const char* __restrict__ A,   // [4096,2048] i8
                                               const char* __restrict__ Bt,  // [4096,2048] i8
                                               u16* __restrict__ C,          // [4096,4096] bf16
                                               const u32* __restrict__ scal) {
  __shared__ __align__(16) char As[2][128 * 128];
  __shared__ __align__(16) char Bs[2][128 * 128];
  const int t = threadIdx.x;
  const int w = t >> 6, l = t & 63;
  const int l15 = l & 15, quad = l >> 4;
  const int xorr = l15 & 7;
  // gm=8 panel swizzle for L2 locality (grid = 1024 1D)
  const int GM = 8, NN = 32, grp = GM * NN;
  int pid = blockIdx.x;
  int gid = pid / grp;
  int mm = gid * GM + (pid % GM);
  int nn = (pid % grp) / GM;
  const int m0 = mm * 128, n0 = nn * 128;
  const int mw = (w & 1) * 64, nw = (w >> 1) * 64;
  v4i acc[4][4] = {};

  // XOR source swizzle so LDS ds_read_b128 spreads over banks (0 conflicts)
  const int srow_lo = l >> 3;
  const int sbg = (l & 7) ^ ((l >> 3) & 7);

  // per-thread staging addresses (row/col within tile are kt-invariant)
  const int srow = (w * 4) * 8 + srow_lo;     // rows srow, srow+8, +16, +24
  const char* ga = A  + (size_t)(m0 + srow) * Kd + sbg * 16;
  const char* gb = Bt + (size_t)(n0 + srow) * Kd + sbg * 16;

  // prologue: stage K-tile 0 into buffer 0
#pragma unroll
  for (int i = 0; i < 4; ++i) {
    async16(ga + (size_t)(i * 8) * Kd, As[0] + (w * 4 + i) * 1024);
    async16(gb + (size_t)(i * 8) * Kd, Bs[0] + (w * 4 + i) * 1024);
  }
  __syncthreads();   // drains vmcnt(0): tile 0 resident

#pragma unroll 2
  for (int kt = 0; kt < 16; ++kt) {
    const char* curA = As[kt & 1];
    const char* curB = Bs[kt & 1];
    // issue next-tile staging into the alternate buffer (flies under compute)
    if (kt + 1 < 16) {
      char* nxtA = (char*)As[(kt + 1) & 1];
      char* nxtB = (char*)Bs[(kt + 1) & 1];
      const size_t kg = (size_t)(kt + 1) * 128;
#pragma unroll
      for (int i = 0; i < 4; ++i) {
        async16(ga + (size_t)(i * 8) * Kd + kg, nxtA + (w * 4 + i) * 1024);
        async16(gb + (size_t)(i * 8) * Kd + kg, nxtB + (w * 4 + i) * 1024);
      }
      __builtin_amdgcn_sched_barrier(0);   // pin: loads issued before compute
    }
#pragma unroll
    for (int kc = 0; kc < 2; ++kc) {
      v4i av[4], bv[4];
#pragma unroll
      for (int mi = 0; mi < 4; ++mi) {
        int row = mw + mi * 16 + l15;
        av[mi] = *(const v4i*)(curA + row * 128 + (((kc * 4 + quad) ^ xorr) * 16));
      }
#pragma unroll
      for (int ni = 0; ni < 4; ++ni) {
        int row = nw + ni * 16 + l15;
        bv[ni] = *(const v4i*)(curB + row * 128 + (((kc * 4 + quad) ^ xorr) * 16));
      }
#pragma unroll
      for (int mi = 0; mi < 4; ++mi)
#pragma unroll
        for (int ni = 0; ni < 4; ++ni)
          acc[mi][ni] = __builtin_amdgcn_mfma_i32_16x16x64_i8(av[mi], bv[ni], acc[mi][ni], 0, 0, 0);
    }
    // one barrier per tile: built-in vmcnt(0) waits only the residual latency
    // not covered by the compute above; also WAR-protects the buffer swap.
    __syncthreads();
  }
  float sx = (__uint_as_float(scal[0]) * 0.015625f) / 127.0f;
  float sw = (__uint_as_float(scal[1]) * 0.015625f) / 127.0f;
  float alpha = sx * sw * (1.0f / 4096.0f);

  // ---- fused epilogue: H64 over row-low bits (Rl) and col-low bits (Cl) ----
  // Wave quadrant = aligned 64x64 tile. row6 = mi*16+quad*4+r, col6 = ni*16+l15.
  // Register-resident bits {r, ni, mi} -> plain fwht64 over flat idx (order-free).
  // Lane-resident bits {l15: lane 0-3, quad: lane 4-5} -> 6 shfl_xor butterflies.
  float vals[64];
#pragma unroll
  for (int mi = 0; mi < 4; ++mi)
#pragma unroll
    for (int ni = 0; ni < 4; ++ni)
#pragma unroll
      for (int r = 0; r < 4; ++r)
        vals[mi * 16 + ni * 4 + r] = (float)acc[mi][ni][r] * alpha;
  fwht64(vals);
#pragma unroll
  for (int k = 0; k < 6; ++k) {
    const int mask = 1 << k;
    const int bit = (l >> k) & 1;
#pragma unroll
    for (int i = 0; i < 64; ++i) {
      float p = __shfl_xor(vals[i], mask, 64);
      vals[i] = bit ? (p - vals[i]) : (vals[i] + p);
    }
  }
#pragma unroll
  for (int mi = 0; mi < 4; ++mi)
#pragma unroll
    for (int ni = 0; ni < 4; ++ni)
#pragma unroll
      for (int r = 0; r < 4; ++r) {
        int row = m0 + mw + mi * 16 + quad * 4 + r;
        int col = n0 + nw + ni * 16 + l15;
        C[(size_t)row * Fd + col] = bf16_rne(vals[mi * 16 + ni * 4 + r]);
      }
}

// ---------------- Output pass Ch: H64 over col-high bits, per-row, bf16 in-place ----
__global__ __launch_bounds__(256) void colhigh_fwht(u16* __restrict__ yr) {
  __shared__ u16 sh[4 * 4096];   // 32768 B = 2048 uint4 -> 8 iters of 256 threads
  const int t = threadIdx.x;
  const size_t row0 = (size_t)blockIdx.x * 4;
  uint4* shv = (uint4*)sh;
  const uint4* g = (const uint4*)(yr + row0 * 4096);
#pragma unroll
  for (int i = 0; i < 8; ++i) shv[t + 256 * i] = g[t + 256 * i];
  __syncthreads();
  const int grp = t >> 6, cl = t & 63;
  const u16* shr = sh + grp * 4096;
  float v[64];
#pragma unroll
  for (int ch = 0; ch < 64; ++ch)
    v[ch] = __uint_as_float(((u32)shr[ch * 64 + cl]) << 16);
  fwht64(v);
  __syncthreads();
  u16* shw = sh + grp * 4096;
#pragma unroll
  for (int ch = 0; ch < 64; ++ch)
    shw[ch * 64 + cl] = bf16_rne(v[ch]);
  __syncthreads();
  uint4* go = (uint4*)(yr + row0 * 4096);
#pragma unroll
  for (int i = 0; i < 8; ++i) go[t + 256 * i] = shv[t + 256 * i];
}

// ---- Output pass Rh (LAST): H64 over stride-64 rows, +bias, f32 out ----
// LDS-staged loads (G13): uint4 global reads instead of scalar u16.
__global__ __launch_bounds__(256) void rowhigh_last(const u16* __restrict__ in,
                                                    float* __restrict__ outf,
                                                    const float* __restrict__ bias) {
  __shared__ u16 tile[64 * 264];   // 64 rows x 256 cols, +8 u16 pad per row
  const int t = threadIdx.x;
  const int c0 = blockIdx.x * 256;          // col chunk base (grid.x = 16)
  const int base = blockIdx.y;              // 0..63
#pragma unroll
  for (int i = 0; i < 8; ++i) {
    int idx = t + 256 * i;                  // 0..2047
    int r = idx >> 5, u = idx & 31;
    uint4 d = *(const uint4*)(in + (size_t)(base + r * 64) * 4096 + c0 + u * 8);
    *(uint4*)(&tile[r * 264 + u * 8]) = d;
  }
  __syncthreads();
  float v[64];
#pragma unroll
  for (int r = 0; r < 64; ++r) v[r] = bf16_f32(tile[r * 264 + t]);
  fwht64(v);
  const int c = c0 + t;
  float b0 = bias[c];
#pragma unroll
  for (int r = 0; r < 64; ++r)
    outf[(size_t)(base + r * 64) * 4096 + c] = v[r] + b0;
}

// ---------------- Launch ----------------
extern "C" void kernel_launch(void* const* d_in, const int* in_sizes, int n_in,
                              void* d_out, int out_size, void* d_ws, size_t ws_size,
                              hipStream_t stream) {
  (void)in_sizes; (void)n_in; (void)out_size; (void)ws_size;
  const float* x       = (const float*)d_in[0];  // [4096,2048]
  const float* w       = (const float*)d_in[1];  // [2048,4096]
  const float* bias    = (const float*)d_in[2];  // [4096]
  const float* noise_x = (const float*)d_in[5];  // [4096,2048]
  const float* noise_w = (const float*)d_in[6];  // [2048,4096]
  char* ws = (char*)d_ws;
  char* qx   = (char*)(ws + OFF_QX);
  char* qwT  = (char*)(ws + OFF_QWT);
  u16*  X1h  = (u16*) (ws + OFF_X1B);
  u32*  W1b  = (u32*) (ws + OFF_W1B);
  u16*  yr   = (u16*) (ws + OFF_YR);
  u32*  scal = (u32*) (ws + OFF_SCAL);
  float* out = (float*)d_out;

  // x rotation: H2 @ x (2 stages, bf16 intermediate); stage1 also zeroes scal
  xcol_s1<<<dim3(8, 64), dim3(256), 0, stream>>>(x, X1h, scal);
  xcol_s2<<<dim3(8, 64), dim3(256), 0, stream>>>(X1h, scal + 0);
  // w rotation: w @ H1 (row FWHT, bf16 out) + max
  roww_fwht<<<dim3(Kd), dim3(256), 0, stream>>>(w, W1b, scal + 1);
  // stochastic int8 quantization
  quant_x_i8<<<dim3(4096), dim3(256), 0, stream>>>(
      (const uint4*)X1h, (const float4*)noise_x, (uint2*)qx, scal);
  quant_w_t_i8<<<dim3(Kd / 64, Fd / 64), dim3(256), 0, stream>>>(
      W1b, (const float2*)noise_w, qwT, scal);
  // core i8 GEMM (2-phase dbuf) -> yr bf16 with fused Rl/Cl output rotation
  gemm_i8<<<dim3((Bd / 128) * (Fd / 128)), dim3(256), 0, stream>>>(qx, qwT, yr, scal);
  // remaining output stages: col-high, then row-high (+bias, f32)
  colhigh_fwht<<<dim3(Bd / 4), dim3(256), 0, stream>>>(yr);
  rowhigh_last<<<dim3(16, 64), dim3(256), 0, stream>>>(yr, out, bias);
}